// Round 1
// baseline (225.392 us; speedup 1.0000x reference)
//
#include <hip/hip_runtime.h>

// reconstruction_loss: charbonnier_mean(get_msfa(X,4), get_msfa(Y,4))
// X, Y: [B=8, C=16, H=512, W=512] fp32. Pixel (b,h,w) gathers channel
// c = (h%4)*4 + (w%4). Loss = mean over B*H*W of sqrt(d^2 + 1e-6).
//
// Memory-bound: needed bytes = 16 MiB, but stride-4 gather forces every
// touched 64B line to be fetched with 1/4 utilization -> 64 MiB HBM floor.

#define EPS_F 1e-6f

constexpr int kBlocks  = 1024;
constexpr int kThreads = 256;
constexpr int kNPix    = 8 * 512 * 512;          // 2097152
constexpr int kPerThr  = kNPix / (kBlocks * kThreads); // 8

__global__ __launch_bounds__(kThreads) void msfa_charb_partial(
    const float* __restrict__ X, const float* __restrict__ Y,
    float* __restrict__ partial)
{
    const int tid      = blockIdx.x * kThreads + threadIdx.x;
    const int nthreads = kBlocks * kThreads;     // 262144

    float acc = 0.0f;
#pragma unroll
    for (int it = 0; it < kPerThr; ++it) {
        const int idx = tid + it * nthreads;     // consecutive lanes -> consecutive pixels
        const int b   = idx >> 18;               // / (512*512)
        const int rem = idx & 0x3FFFF;
        const int h   = rem >> 9;                // / 512
        const int w   = rem & 511;
        const int c   = ((h & 3) << 2) | (w & 3);
        const int off = (((b << 4) + c) << 18) + (h << 9) + w;
        const float d = X[off] - Y[off];
        acc += sqrtf(d * d + EPS_F);
    }

    // wave64 butterfly reduce
#pragma unroll
    for (int s = 32; s > 0; s >>= 1)
        acc += __shfl_down(acc, s, 64);

    __shared__ float sdata[kThreads / 64];
    const int lane = threadIdx.x & 63;
    const int wave = threadIdx.x >> 6;
    if (lane == 0) sdata[wave] = acc;
    __syncthreads();
    if (threadIdx.x == 0) {
        float t = 0.0f;
#pragma unroll
        for (int i = 0; i < kThreads / 64; ++i) t += sdata[i];
        partial[blockIdx.x] = t;
    }
}

__global__ __launch_bounds__(1024) void msfa_finalize(
    const float* __restrict__ partial, float* __restrict__ out)
{
    float v = partial[threadIdx.x];              // 1024 partials, 1024 threads
#pragma unroll
    for (int s = 32; s > 0; s >>= 1)
        v += __shfl_down(v, s, 64);

    __shared__ float sdata[16];
    const int lane = threadIdx.x & 63;
    const int wave = threadIdx.x >> 6;
    if (lane == 0) sdata[wave] = v;
    __syncthreads();
    if (threadIdx.x == 0) {
        float t = 0.0f;
#pragma unroll
        for (int i = 0; i < 16; ++i) t += sdata[i];
        out[0] = t * (1.0f / (float)kNPix);
    }
}

extern "C" void kernel_launch(void* const* d_in, const int* in_sizes, int n_in,
                              void* d_out, int out_size, void* d_ws, size_t ws_size,
                              hipStream_t stream)
{
    const float* X = (const float*)d_in[0];
    const float* Y = (const float*)d_in[1];
    float* partial = (float*)d_ws;               // kBlocks floats = 4 KiB scratch
    float* out     = (float*)d_out;

    msfa_charb_partial<<<kBlocks, kThreads, 0, stream>>>(X, Y, partial);
    msfa_finalize<<<1, 1024, 0, stream>>>(partial, out);
}